// Round 4
// baseline (293.204 us; speedup 1.0000x reference)
//
#include <hip/hip_runtime.h>
#include <hip/hip_bf16.h>

// K=64 clouds, d=320 feats, N=2048 pts, M=128 clusters, S=8192 segments.
#define KC 64
#define DD 320
#define NP 2048
#define MC 128
#define SS (KC * MC)
#define EPSV 1e-12f

// means kernel geometry
#define CHUNKF 20            // features per block
#define NCHUNKF 16           // 320 / 20
#define GFEAT 4              // features staged per group
#define NGROUP 5             // CHUNKF / GFEAT
#define TILEW 2176           // 2048 + 2048/16 (skewed width)

#define TAILB 128            // tail kernel blocks (<= CU count: co-resident)

// ---------------------------------------------------------------------------
// Kernel A: per-cloud counting sort + cluster stats (no global atomics).
// Also zeroes the tail kernel's barrier counters (runs 2 dispatches earlier).
// ---------------------------------------------------------------------------
__global__ __launch_bounds__(256) void sortstats_kernel(
    const float* __restrict__ label,       // (K, N)
    const int* __restrict__ clab,          // (K, N)
    unsigned short* __restrict__ spos_ws,  // (K, N) skewed sorted pos
    int* __restrict__ starts_ws,           // (K, 129)
    float* __restrict__ cls_ws,            // (S,)
    float* __restrict__ sizes_ws,          // (S,)
    float* __restrict__ kmax_ws,           // (K,) per-cloud max masked size
    float* __restrict__ kval_ws,           // (K,) per-cloud n_valid
    unsigned* __restrict__ counters)       // [2] barrier counters -> zero
{
    const int k = blockIdx.x;
    const int tid = threadIdx.x;

    if (k == 0 && tid == 0) { counters[0] = 0u; counters[1] = 0u; }

    __shared__ int   s_cnt[MC];
    __shared__ float s_lbl[MC];
    __shared__ int   s_scan[MC + 1];
    __shared__ float s_red[256];

    if (tid < MC) { s_cnt[tid] = 0; s_lbl[tid] = 0.f; }
    __syncthreads();

    int id[8], rk[8];
#pragma unroll
    for (int i = 0; i < 8; ++i) {
        const int p = i * 256 + tid;
        id[i] = clab[k * NP + p];
        rk[i] = atomicAdd(&s_cnt[id[i]], 1);
        unsafeAtomicAdd(&s_lbl[id[i]], label[k * NP + p]);
    }
    __syncthreads();

    // exclusive scan of counts -> starts
    if (tid < MC) s_scan[tid + 1] = s_cnt[tid];
    if (tid == 0) s_scan[0] = 0;
    __syncthreads();
    for (int off = 1; off < MC; off <<= 1) {
        int v = 0;
        if (tid < MC && (tid + 1) > off) v = s_scan[tid + 1 - off];
        __syncthreads();
        if (tid < MC) s_scan[tid + 1] += v;
        __syncthreads();
    }

    // per-cluster stats
    float localmax = 0.f, localval = 0.f;
    if (tid < MC) {
        const int c = s_cnt[tid];
        const float lm = s_lbl[tid] / fmaxf((float)c, 1.f);
        const bool is = (lm > 0.5f) && (c > 0);
        const float sz = is ? (float)c : 0.f;
        cls_ws[k * MC + tid] = is ? 1.f : 0.f;
        sizes_ws[k * MC + tid] = sz;
        localmax = sz;
        localval = is ? 1.f : 0.f;
    }
    s_red[tid] = localmax;
    __syncthreads();
    for (int off = 128; off > 0; off >>= 1) {
        if (tid < off) s_red[tid] = fmaxf(s_red[tid], s_red[tid + off]);
        __syncthreads();
    }
    if (tid == 0) kmax_ws[k] = s_red[0];
    __syncthreads();
    s_red[tid] = localval;
    __syncthreads();
    for (int off = 128; off > 0; off >>= 1) {
        if (tid < off) s_red[tid] += s_red[tid + off];
        __syncthreads();
    }
    if (tid == 0) kval_ws[k] = s_red[0];

    // outputs: starts + skewed sorted positions
    for (int i = tid; i < MC + 1; i += 256) starts_ws[k * (MC + 1) + i] = s_scan[i];
#pragma unroll
    for (int i = 0; i < 8; ++i) {
        const int p = i * 256 + tid;
        const int sp0 = s_scan[id[i]] + rk[i];
        spos_ws[k * NP + p] = (unsigned short)(sp0 + (sp0 >> 4));
    }
}

// ---------------------------------------------------------------------------
// Kernel B: segment means. Block = (cloud k, 20-feature chunk). Double-buffered:
// coalesced float4 loads -> plain ds_write scatter to skewed sorted positions ->
// contiguous per-(cluster, feature) segment sums from LDS. No atomics.
// ---------------------------------------------------------------------------
__global__ __launch_bounds__(512) void means_kernel(
    const float* __restrict__ feat,           // (K, d, N)
    const unsigned short* __restrict__ spos_ws,
    const int* __restrict__ starts_ws,
    float* __restrict__ means_out)            // (S, d)
{
    const int k = blockIdx.x;
    const int chunk = blockIdx.y;
    const int tid = threadIdx.x;

    __shared__ float s_tile[2][GFEAT][TILEW];   // 69.6 KB
    __shared__ unsigned short s_sp[NP];         // 4 KB
    __shared__ int s_starts[MC + 1];

    {
        const unsigned* spg = (const unsigned*)(spos_ws + (size_t)k * NP);
        for (int i = tid; i < NP / 2; i += 512) ((unsigned*)s_sp)[i] = spg[i];
        if (tid < MC + 1) s_starts[tid] = starts_ws[k * (MC + 1) + tid];
    }
    __syncthreads();

    const int m = tid & 127;   // cluster / staging column group
    const int r = tid >> 7;    // 0..3: feature within group

    unsigned short sp[16];
#pragma unroll
    for (int q = 0; q < 4; ++q) {
        const int p0 = (m + 128 * q) * 4;
#pragma unroll
        for (int e = 0; e < 4; ++e) sp[4 * q + e] = s_sp[p0 + e];
    }

    const int st = s_starts[m];
    const int en = s_starts[m + 1];
    const float invd = 1.0f / fmaxf((float)(en - st), 1.0f);

    const float* fb = feat + (size_t)k * DD * NP + (size_t)chunk * CHUNKF * NP;
    float regsum[NGROUP];
    float4 ld[4];

    // prologue: load + stage group 0
    {
        const float4* src = (const float4*)(fb + (size_t)r * NP);
#pragma unroll
        for (int q = 0; q < 4; ++q) ld[q] = src[m + 128 * q];
#pragma unroll
        for (int q = 0; q < 4; ++q) {
            s_tile[0][r][sp[4 * q + 0]] = ld[q].x;
            s_tile[0][r][sp[4 * q + 1]] = ld[q].y;
            s_tile[0][r][sp[4 * q + 2]] = ld[q].z;
            s_tile[0][r][sp[4 * q + 3]] = ld[q].w;
        }
    }
    __syncthreads();

#pragma unroll
    for (int g = 0; g < NGROUP; ++g) {
        const int cur = g & 1;
        if (g + 1 < NGROUP) {
            const float4* src = (const float4*)(fb + (size_t)((g + 1) * GFEAT + r) * NP);
#pragma unroll
            for (int q = 0; q < 4; ++q) ld[q] = src[m + 128 * q];
        }
        float acc = 0.f;
        for (int qq = st; qq < en; ++qq) {
            acc += s_tile[cur][r][qq + (qq >> 4)];
        }
        regsum[g] = acc;
        if (g + 1 < NGROUP) {
#pragma unroll
            for (int q = 0; q < 4; ++q) {
                s_tile[cur ^ 1][r][sp[4 * q + 0]] = ld[q].x;
                s_tile[cur ^ 1][r][sp[4 * q + 1]] = ld[q].y;
                s_tile[cur ^ 1][r][sp[4 * q + 2]] = ld[q].z;
                s_tile[cur ^ 1][r][sp[4 * q + 3]] = ld[q].w;
            }
        }
        __syncthreads();
    }

    float* mrow = means_out + (size_t)(k * MC + m) * DD + chunk * CHUNKF;
#pragma unroll
    for (int g = 0; g < NGROUP; ++g) mrow[g * GFEAT + r] = regsum[g] * invd;
}

// ---------------------------------------------------------------------------
// Software grid barrier for co-resident blocks (device-scope, XCD-safe).
// ---------------------------------------------------------------------------
__device__ inline void grid_barrier(unsigned* cnt, unsigned nblocks) {
    __syncthreads();   // all waves' stores drained to L2 before the release
    if (threadIdx.x == 0) {
        __hip_atomic_fetch_add(cnt, 1u, __ATOMIC_ACQ_REL, __HIP_MEMORY_SCOPE_AGENT);
        while (__hip_atomic_load(cnt, __ATOMIC_ACQUIRE, __HIP_MEMORY_SCOPE_AGENT) < nblocks) {
            __builtin_amdgcn_s_sleep(2);
        }
    }
    __syncthreads();
}

// ---------------------------------------------------------------------------
// Kernel C (fused tail): norm + v-reduce + sim + mean + clean.
// 128 blocks, each owns 64 segments (16 per wave). rw and sim stay in
// registers across phases; two grid barriers.
// ---------------------------------------------------------------------------
__global__ __launch_bounds__(256) void tail_kernel(
    const float* __restrict__ means,   // (S, d)
    const float* __restrict__ cls,     // (S,)
    const float* __restrict__ sizes,   // (S,)
    const float* __restrict__ kmax,    // (K,)
    const float* __restrict__ kval,    // (K,)
    float* __restrict__ vpart,         // (128, d)
    float* __restrict__ simpart,       // (128,)
    unsigned* __restrict__ counters,   // [2]
    float* __restrict__ sim_out,       // (S,)
    float* __restrict__ clean_out)     // (S,)
{
    const int b = blockIdx.x;
    const int tid = threadIdx.x;
    const int wid = tid >> 6;
    const int lane = tid & 63;
    const int seg0 = b * 64 + wid * 16;

    __shared__ float vtmp[4][DD];
    __shared__ float s_v[DD];
    __shared__ float stmp[4];
    __shared__ float s_rmx, s_nvalid, s_mean;

    // block-wide: rmx = 1/max(sizes), nvalid (reduce the 64 per-cloud partials)
    if (wid == 0) {
        float mv = kmax[lane];
        float nv = kval[lane];
#pragma unroll
        for (int off = 32; off > 0; off >>= 1) {
            mv = fmaxf(mv, __shfl_xor(mv, off, 64));
            nv += __shfl_xor(nv, off, 64);
        }
        if (lane == 0) {
            s_rmx = 1.0f / fmaxf(mv, 1.0f);
            s_nvalid = fmaxf(nv, 1.0f);
        }
    }
    __syncthreads();
    const float rmx = s_rmx;

    // ---- phase 1: norms, rw (regs), v partial ----
    float rw[16];
    float vacc[5] = {0.f, 0.f, 0.f, 0.f, 0.f};
#pragma unroll
    for (int i = 0; i < 16; ++i) {
        const int s = seg0 + i;
        const float* row = means + (size_t)s * DD;
        float val[5];
        float ssum = 0.f;
#pragma unroll
        for (int r = 0; r < 5; ++r) {
            val[r] = row[r * 64 + lane];
            ssum = fmaf(val[r], val[r], ssum);
        }
#pragma unroll
        for (int off = 32; off > 0; off >>= 1) ssum += __shfl_xor(ssum, off, 64);
        const float inv = 1.f / fmaxf(sqrtf(ssum), EPSV);
        rw[i] = cls[s] * inv;                 // uniform across lanes
        const float coef = sizes[s] * rmx * rw[i];
#pragma unroll
        for (int r = 0; r < 5; ++r) vacc[r] = fmaf(coef, val[r], vacc[r]);
    }
#pragma unroll
    for (int r = 0; r < 5; ++r) vtmp[wid][r * 64 + lane] = vacc[r];
    __syncthreads();
    for (int j = tid; j < DD; j += 256) {
        vpart[(size_t)b * DD + j] = vtmp[0][j] + vtmp[1][j] + vtmp[2][j] + vtmp[3][j];
    }

    grid_barrier(&counters[0], TAILB);

    // ---- phase 2: reduce v (coalesced across lanes), then sim ----
    for (int j = tid; j < DD; j += 256) {
        float acc = 0.f;
        for (int bb = 0; bb < TAILB; ++bb) acc += vpart[(size_t)bb * DD + j];
        s_v[j] = acc;
    }
    __syncthreads();

    float vreg[5];
#pragma unroll
    for (int r = 0; r < 5; ++r) vreg[r] = s_v[r * 64 + lane];

    float sim[16];
    float lsum = 0.f;
#pragma unroll
    for (int i = 0; i < 16; ++i) {
        const int s = seg0 + i;
        const float* row = means + (size_t)s * DD;
        float dot = 0.f;
#pragma unroll
        for (int r = 0; r < 5; ++r) dot = fmaf(row[r * 64 + lane], vreg[r], dot);
#pragma unroll
        for (int off = 32; off > 0; off >>= 1) dot += __shfl_xor(dot, off, 64);
        sim[i] = rw[i] * dot;                 // uniform across lanes
        lsum += sim[i];                       // non-class rows contribute 0
        if (lane == 0) sim_out[s] = sim[i];
    }
    if (lane == 0) stmp[wid] = lsum;
    __syncthreads();
    if (tid == 0) simpart[b] = stmp[0] + stmp[1] + stmp[2] + stmp[3];

    grid_barrier(&counters[1], TAILB);

    // ---- phase 3: mean score + clean mask ----
    if (wid == 0) {
        float t = simpart[lane] + simpart[lane + 64];
#pragma unroll
        for (int off = 32; off > 0; off >>= 1) t += __shfl_xor(t, off, 64);
        if (lane == 0) s_mean = t / s_nvalid;
    }
    __syncthreads();
    const float mean = s_mean;
    if (lane == 0) {
#pragma unroll
        for (int i = 0; i < 16; ++i) {
            clean_out[seg0 + i] = (sim[i] > mean && rw[i] > 0.f) ? 1.f : 0.f;
        }
    }
}

extern "C" void kernel_launch(void* const* d_in, const int* in_sizes, int n_in,
                              void* d_out, int out_size, void* d_ws, size_t ws_size,
                              hipStream_t stream) {
    const float* feat  = (const float*)d_in[0];
    const float* label = (const float*)d_in[1];
    const int*   clab  = (const int*)d_in[2];

    float* out       = (float*)d_out;
    float* means_out = out;
    float* sim_out   = out + (size_t)SS * DD;
    float* clean_out = sim_out + SS;

    // workspace layout (floats)
    float* ws = (float*)d_ws;
    unsigned* counters = (unsigned*)&ws[0];          // 2 u32
    float* kmax    = &ws[4];                         // 64
    float* kval    = &ws[68];                        // 64
    float* simpart = &ws[132];                       // 128
    float* vpart   = &ws[260];                       // 128*320
    float* cls     = vpart + TAILB * DD;             // 8192
    float* sizes   = cls + SS;                       // 8192
    int*   starts  = (int*)(sizes + SS);             // 64*129
    unsigned short* spos = (unsigned short*)(starts + KC * (MC + 1)); // 64*2048 u16

    sortstats_kernel<<<KC, 256, 0, stream>>>(label, clab, spos, starts,
                                             cls, sizes, kmax, kval, counters);
    means_kernel<<<dim3(KC, NCHUNKF), 512, 0, stream>>>(feat, spos, starts, means_out);
    tail_kernel<<<TAILB, 256, 0, stream>>>(means_out, cls, sizes, kmax, kval,
                                           vpart, simpart, counters,
                                           sim_out, clean_out);
}

// Round 5
// 292.602 us; speedup vs baseline: 1.0021x; 1.0021x over previous
//
#include <hip/hip_runtime.h>
#include <hip/hip_bf16.h>

// K=64 clouds, d=320 feats, N=2048 pts, M=128 clusters, S=8192 segments.
#define KC 64
#define DD 320
#define NP 2048
#define MC 128
#define SS (KC * MC)
#define EPSV 1e-12f

// means kernel geometry
#define CHUNKF 20            // features per block
#define NCHUNKF 16           // 320 / 20
#define GFEAT 4              // features staged per group
#define NGROUP 5             // CHUNKF / GFEAT
#define TILEW 2176           // 2048 + 2048/16 (skewed width)

#define TAILB 128            // tail kernel blocks (co-resident)

// ---------------------------------------------------------------------------
// Kernel A: per-cloud counting sort + cluster stats (no global atomics).
// Also zeroes the tail kernel's barrier counters (runs 2 dispatches earlier).
// ---------------------------------------------------------------------------
__global__ __launch_bounds__(256) void sortstats_kernel(
    const float* __restrict__ label,       // (K, N)
    const int* __restrict__ clab,          // (K, N)
    unsigned short* __restrict__ spos_ws,  // (K, N) skewed sorted pos
    int* __restrict__ starts_ws,           // (K, 129)
    float* __restrict__ cls_ws,            // (S,)
    float* __restrict__ sizes_ws,          // (S,)
    float* __restrict__ kmax_ws,           // (K,) per-cloud max masked size
    float* __restrict__ kval_ws,           // (K,) per-cloud n_valid
    unsigned* __restrict__ counters)       // [2] barrier counters -> zero
{
    const int k = blockIdx.x;
    const int tid = threadIdx.x;

    if (k == 0 && tid == 0) { counters[0] = 0u; counters[1] = 0u; }

    __shared__ int   s_cnt[MC];
    __shared__ float s_lbl[MC];
    __shared__ int   s_scan[MC + 1];
    __shared__ float s_red[256];

    if (tid < MC) { s_cnt[tid] = 0; s_lbl[tid] = 0.f; }
    __syncthreads();

    int id[8], rk[8];
#pragma unroll
    for (int i = 0; i < 8; ++i) {
        const int p = i * 256 + tid;
        id[i] = clab[k * NP + p];
        rk[i] = atomicAdd(&s_cnt[id[i]], 1);
        unsafeAtomicAdd(&s_lbl[id[i]], label[k * NP + p]);
    }
    __syncthreads();

    // exclusive scan of counts -> starts
    if (tid < MC) s_scan[tid + 1] = s_cnt[tid];
    if (tid == 0) s_scan[0] = 0;
    __syncthreads();
    for (int off = 1; off < MC; off <<= 1) {
        int v = 0;
        if (tid < MC && (tid + 1) > off) v = s_scan[tid + 1 - off];
        __syncthreads();
        if (tid < MC) s_scan[tid + 1] += v;
        __syncthreads();
    }

    // per-cluster stats
    float localmax = 0.f, localval = 0.f;
    if (tid < MC) {
        const int c = s_cnt[tid];
        const float lm = s_lbl[tid] / fmaxf((float)c, 1.f);
        const bool is = (lm > 0.5f) && (c > 0);
        const float sz = is ? (float)c : 0.f;
        cls_ws[k * MC + tid] = is ? 1.f : 0.f;
        sizes_ws[k * MC + tid] = sz;
        localmax = sz;
        localval = is ? 1.f : 0.f;
    }
    s_red[tid] = localmax;
    __syncthreads();
    for (int off = 128; off > 0; off >>= 1) {
        if (tid < off) s_red[tid] = fmaxf(s_red[tid], s_red[tid + off]);
        __syncthreads();
    }
    if (tid == 0) kmax_ws[k] = s_red[0];
    __syncthreads();
    s_red[tid] = localval;
    __syncthreads();
    for (int off = 128; off > 0; off >>= 1) {
        if (tid < off) s_red[tid] += s_red[tid + off];
        __syncthreads();
    }
    if (tid == 0) kval_ws[k] = s_red[0];

    // outputs: starts + skewed sorted positions
    for (int i = tid; i < MC + 1; i += 256) starts_ws[k * (MC + 1) + i] = s_scan[i];
#pragma unroll
    for (int i = 0; i < 8; ++i) {
        const int p = i * 256 + tid;
        const int sp0 = s_scan[id[i]] + rk[i];
        spos_ws[k * NP + p] = (unsigned short)(sp0 + (sp0 >> 4));
    }
}

// ---------------------------------------------------------------------------
// Kernel B: segment means. Block = (cloud k, 20-feature chunk).
// SINGLE-buffered tile (38.5 KB LDS -> 4 blocks/CU, 100% occupancy): loads for
// group g issue BEFORE the barrier protecting the overwrite, so HBM latency
// overlaps the previous group's accumulate across 32 resident waves/CU.
// ---------------------------------------------------------------------------
__global__ __launch_bounds__(512, 8) void means_kernel(
    const float* __restrict__ feat,           // (K, d, N)
    const unsigned short* __restrict__ spos_ws,
    const int* __restrict__ starts_ws,
    float* __restrict__ means_out)            // (S, d)
{
    const int k = blockIdx.x;
    const int chunk = blockIdx.y;
    const int tid = threadIdx.x;

    __shared__ float s_tile[GFEAT][TILEW];      // 34.8 KB
    __shared__ unsigned short s_sp[NP];         // 4 KB
    __shared__ int s_starts[MC + 1];

    {
        const unsigned* spg = (const unsigned*)(spos_ws + (size_t)k * NP);
        for (int i = tid; i < NP / 2; i += 512) ((unsigned*)s_sp)[i] = spg[i];
        if (tid < MC + 1) s_starts[tid] = starts_ws[k * (MC + 1) + tid];
    }
    __syncthreads();

    const int m = tid & 127;   // cluster / staging column group
    const int r = tid >> 7;    // 0..3: feature within group

    unsigned short sp[16];
#pragma unroll
    for (int q = 0; q < 4; ++q) {
        const int p0 = (m + 128 * q) * 4;
#pragma unroll
        for (int e = 0; e < 4; ++e) sp[4 * q + e] = s_sp[p0 + e];
    }

    const int st = s_starts[m];
    const int en = s_starts[m + 1];
    const float invd = 1.0f / fmaxf((float)(en - st), 1.0f);

    const float* fb = feat + (size_t)k * DD * NP + (size_t)chunk * CHUNKF * NP;
    float regsum[NGROUP];

#pragma unroll
    for (int g = 0; g < NGROUP; ++g) {
        // issue loads first: latency overlaps prior accumulate + barrier wait
        const float4* src = (const float4*)(fb + (size_t)(g * GFEAT + r) * NP);
        float4 ld[4];
#pragma unroll
        for (int q = 0; q < 4; ++q) ld[q] = src[m + 128 * q];
        if (g > 0) __syncthreads();   // prior accumulate done before overwrite
#pragma unroll
        for (int q = 0; q < 4; ++q) {
            s_tile[r][sp[4 * q + 0]] = ld[q].x;
            s_tile[r][sp[4 * q + 1]] = ld[q].y;
            s_tile[r][sp[4 * q + 2]] = ld[q].z;
            s_tile[r][sp[4 * q + 3]] = ld[q].w;
        }
        __syncthreads();
        // contiguous segment sum for (cluster m, feature g*4+r)
        float acc = 0.f;
        for (int qq = st; qq < en; ++qq) {
            acc += s_tile[r][qq + (qq >> 4)];
        }
        regsum[g] = acc;
    }

    float* mrow = means_out + (size_t)(k * MC + m) * DD + chunk * CHUNKF;
#pragma unroll
    for (int g = 0; g < NGROUP; ++g) mrow[g * GFEAT + r] = regsum[g] * invd;
}

// ---------------------------------------------------------------------------
// Software grid barrier for co-resident blocks (device-scope, XCD-safe).
// ---------------------------------------------------------------------------
__device__ inline void grid_barrier(unsigned* cnt, unsigned nblocks) {
    __syncthreads();   // all waves' stores drained before the release
    if (threadIdx.x == 0) {
        __hip_atomic_fetch_add(cnt, 1u, __ATOMIC_ACQ_REL, __HIP_MEMORY_SCOPE_AGENT);
        while (__hip_atomic_load(cnt, __ATOMIC_ACQUIRE, __HIP_MEMORY_SCOPE_AGENT) < nblocks) {
            __builtin_amdgcn_s_sleep(2);
        }
    }
    __syncthreads();
}

// ---------------------------------------------------------------------------
// Kernel C (fused tail): norm + v-reduce + sim + mean + clean.
// 128 blocks, each owns 64 segments (16 per wave). rw and sim stay in
// registers across phases; two grid barriers.
// ---------------------------------------------------------------------------
__global__ __launch_bounds__(256) void tail_kernel(
    const float* __restrict__ means,   // (S, d)
    const float* __restrict__ cls,     // (S,)
    const float* __restrict__ sizes,   // (S,)
    const float* __restrict__ kmax,    // (K,)
    const float* __restrict__ kval,    // (K,)
    float* __restrict__ vpart,         // (128, d)
    float* __restrict__ simpart,       // (128,)
    unsigned* __restrict__ counters,   // [2]
    float* __restrict__ sim_out,       // (S,)
    float* __restrict__ clean_out)     // (S,)
{
    const int b = blockIdx.x;
    const int tid = threadIdx.x;
    const int wid = tid >> 6;
    const int lane = tid & 63;
    const int seg0 = b * 64 + wid * 16;

    __shared__ float vtmp[4][DD];
    __shared__ float s_v[DD];
    __shared__ float stmp[4];
    __shared__ float s_rmx, s_nvalid, s_mean;

    if (wid == 0) {
        float mv = kmax[lane];
        float nv = kval[lane];
#pragma unroll
        for (int off = 32; off > 0; off >>= 1) {
            mv = fmaxf(mv, __shfl_xor(mv, off, 64));
            nv += __shfl_xor(nv, off, 64);
        }
        if (lane == 0) {
            s_rmx = 1.0f / fmaxf(mv, 1.0f);
            s_nvalid = fmaxf(nv, 1.0f);
        }
    }
    __syncthreads();
    const float rmx = s_rmx;

    // ---- phase 1: norms, rw (regs), v partial ----
    float rw[16];
    float vacc[5] = {0.f, 0.f, 0.f, 0.f, 0.f};
#pragma unroll
    for (int i = 0; i < 16; ++i) {
        const int s = seg0 + i;
        const float* row = means + (size_t)s * DD;
        float val[5];
        float ssum = 0.f;
#pragma unroll
        for (int r = 0; r < 5; ++r) {
            val[r] = row[r * 64 + lane];
            ssum = fmaf(val[r], val[r], ssum);
        }
#pragma unroll
        for (int off = 32; off > 0; off >>= 1) ssum += __shfl_xor(ssum, off, 64);
        const float inv = 1.f / fmaxf(sqrtf(ssum), EPSV);
        rw[i] = cls[s] * inv;
        const float coef = sizes[s] * rmx * rw[i];
#pragma unroll
        for (int r = 0; r < 5; ++r) vacc[r] = fmaf(coef, val[r], vacc[r]);
    }
#pragma unroll
    for (int r = 0; r < 5; ++r) vtmp[wid][r * 64 + lane] = vacc[r];
    __syncthreads();
    for (int j = tid; j < DD; j += 256) {
        vpart[(size_t)b * DD + j] = vtmp[0][j] + vtmp[1][j] + vtmp[2][j] + vtmp[3][j];
    }

    grid_barrier(&counters[0], TAILB);

    // ---- phase 2: reduce v, then sim ----
    for (int j = tid; j < DD; j += 256) {
        float acc = 0.f;
        for (int bb = 0; bb < TAILB; ++bb) acc += vpart[(size_t)bb * DD + j];
        s_v[j] = acc;
    }
    __syncthreads();

    float vreg[5];
#pragma unroll
    for (int r = 0; r < 5; ++r) vreg[r] = s_v[r * 64 + lane];

    float sim[16];
    float lsum = 0.f;
#pragma unroll
    for (int i = 0; i < 16; ++i) {
        const int s = seg0 + i;
        const float* row = means + (size_t)s * DD;
        float dot = 0.f;
#pragma unroll
        for (int r = 0; r < 5; ++r) dot = fmaf(row[r * 64 + lane], vreg[r], dot);
#pragma unroll
        for (int off = 32; off > 0; off >>= 1) dot += __shfl_xor(dot, off, 64);
        sim[i] = rw[i] * dot;
        lsum += sim[i];
        if (lane == 0) sim_out[s] = sim[i];
    }
    if (lane == 0) stmp[wid] = lsum;
    __syncthreads();
    if (tid == 0) simpart[b] = stmp[0] + stmp[1] + stmp[2] + stmp[3];

    grid_barrier(&counters[1], TAILB);

    // ---- phase 3: mean score + clean mask ----
    if (wid == 0) {
        float t = simpart[lane] + simpart[lane + 64];
#pragma unroll
        for (int off = 32; off > 0; off >>= 1) t += __shfl_xor(t, off, 64);
        if (lane == 0) s_mean = t / s_nvalid;
    }
    __syncthreads();
    const float mean = s_mean;
    if (lane == 0) {
#pragma unroll
        for (int i = 0; i < 16; ++i) {
            clean_out[seg0 + i] = (sim[i] > mean && rw[i] > 0.f) ? 1.f : 0.f;
        }
    }
}

extern "C" void kernel_launch(void* const* d_in, const int* in_sizes, int n_in,
                              void* d_out, int out_size, void* d_ws, size_t ws_size,
                              hipStream_t stream) {
    const float* feat  = (const float*)d_in[0];
    const float* label = (const float*)d_in[1];
    const int*   clab  = (const int*)d_in[2];

    float* out       = (float*)d_out;
    float* means_out = out;
    float* sim_out   = out + (size_t)SS * DD;
    float* clean_out = sim_out + SS;

    // workspace layout (floats)
    float* ws = (float*)d_ws;
    unsigned* counters = (unsigned*)&ws[0];          // 2 u32
    float* kmax    = &ws[4];                         // 64
    float* kval    = &ws[68];                        // 64
    float* simpart = &ws[132];                       // 128
    float* vpart   = &ws[260];                       // 128*320
    float* cls     = vpart + TAILB * DD;             // 8192
    float* sizes   = cls + SS;                       // 8192
    int*   starts  = (int*)(sizes + SS);             // 64*129
    unsigned short* spos = (unsigned short*)(starts + KC * (MC + 1)); // 64*2048 u16

    sortstats_kernel<<<KC, 256, 0, stream>>>(label, clab, spos, starts,
                                             cls, sizes, kmax, kval, counters);
    means_kernel<<<dim3(KC, NCHUNKF), 512, 0, stream>>>(feat, spos, starts, means_out);
    tail_kernel<<<TAILB, 256, 0, stream>>>(means_out, cls, sizes, kmax, kval,
                                           vpart, simpart, counters,
                                           sim_out, clean_out);
}

// Round 6
// 292.543 us; speedup vs baseline: 1.0023x; 1.0002x over previous
//
#include <hip/hip_runtime.h>
#include <hip/hip_bf16.h>

// K=64 clouds, d=320 feats, N=2048 pts, M=128 clusters, S=8192 segments.
#define KC 64
#define DD 320
#define NP 2048
#define MC 128
#define SS (KC * MC)
#define EPSV 1e-12f

// means kernel geometry
#define CHUNKF 20            // features per block
#define NCHUNKF 16           // 320 / 20
#define GFEAT 4              // features staged per group
#define NGROUP 5             // CHUNKF / GFEAT
#define TILEW 2176           // 2048 + 128 pad slots (skew: a = q + q/16)

#define TAILB 128            // tail kernel blocks (co-resident)

// ---------------------------------------------------------------------------
// Kernel A: per-cloud counting sort + cluster stats (no global atomics).
// Also zeroes the tail kernel's barrier counters (runs 2 dispatches earlier).
// ---------------------------------------------------------------------------
__global__ __launch_bounds__(256) void sortstats_kernel(
    const float* __restrict__ label,       // (K, N)
    const int* __restrict__ clab,          // (K, N)
    unsigned short* __restrict__ spos_ws,  // (K, N) skewed sorted pos
    int* __restrict__ starts_ws,           // (K, 129)
    float* __restrict__ cls_ws,            // (S,)
    float* __restrict__ sizes_ws,          // (S,)
    float* __restrict__ kmax_ws,           // (K,) per-cloud max masked size
    float* __restrict__ kval_ws,           // (K,) per-cloud n_valid
    unsigned* __restrict__ counters)       // [2] barrier counters -> zero
{
    const int k = blockIdx.x;
    const int tid = threadIdx.x;

    if (k == 0 && tid == 0) { counters[0] = 0u; counters[1] = 0u; }

    __shared__ int   s_cnt[MC];
    __shared__ float s_lbl[MC];
    __shared__ int   s_scan[MC + 1];
    __shared__ float s_red[256];

    if (tid < MC) { s_cnt[tid] = 0; s_lbl[tid] = 0.f; }
    __syncthreads();

    int id[8], rk[8];
#pragma unroll
    for (int i = 0; i < 8; ++i) {
        const int p = i * 256 + tid;
        id[i] = clab[k * NP + p];
        rk[i] = atomicAdd(&s_cnt[id[i]], 1);
        unsafeAtomicAdd(&s_lbl[id[i]], label[k * NP + p]);
    }
    __syncthreads();

    // exclusive scan of counts -> starts
    if (tid < MC) s_scan[tid + 1] = s_cnt[tid];
    if (tid == 0) s_scan[0] = 0;
    __syncthreads();
    for (int off = 1; off < MC; off <<= 1) {
        int v = 0;
        if (tid < MC && (tid + 1) > off) v = s_scan[tid + 1 - off];
        __syncthreads();
        if (tid < MC) s_scan[tid + 1] += v;
        __syncthreads();
    }

    // per-cluster stats
    float localmax = 0.f, localval = 0.f;
    if (tid < MC) {
        const int c = s_cnt[tid];
        const float lm = s_lbl[tid] / fmaxf((float)c, 1.f);
        const bool is = (lm > 0.5f) && (c > 0);
        const float sz = is ? (float)c : 0.f;
        cls_ws[k * MC + tid] = is ? 1.f : 0.f;
        sizes_ws[k * MC + tid] = sz;
        localmax = sz;
        localval = is ? 1.f : 0.f;
    }
    s_red[tid] = localmax;
    __syncthreads();
    for (int off = 128; off > 0; off >>= 1) {
        if (tid < off) s_red[tid] = fmaxf(s_red[tid], s_red[tid + off]);
        __syncthreads();
    }
    if (tid == 0) kmax_ws[k] = s_red[0];
    __syncthreads();
    s_red[tid] = localval;
    __syncthreads();
    for (int off = 128; off > 0; off >>= 1) {
        if (tid < off) s_red[tid] += s_red[tid + off];
        __syncthreads();
    }
    if (tid == 0) kval_ws[k] = s_red[0];

    // outputs: starts + skewed sorted positions
    for (int i = tid; i < MC + 1; i += 256) starts_ws[k * (MC + 1) + i] = s_scan[i];
#pragma unroll
    for (int i = 0; i < 8; ++i) {
        const int p = i * 256 + tid;
        const int sp0 = s_scan[id[i]] + rk[i];
        spos_ws[k * NP + p] = (unsigned short)(sp0 + (sp0 >> 4));
    }
}

// ---------------------------------------------------------------------------
// Kernel B: segment means. Block = (cloud k, 20-feature chunk).
// Single-buffered tile, 4 blocks/CU. Pad slots (addr = 17j+16) are zeroed
// ONCE at start and never written by the scatter, so each segment's skewed
// range [st+(st>>4), en+(en>>4)) is dense -> float4 LDS segment sums.
// ---------------------------------------------------------------------------
__global__ __launch_bounds__(512, 8) void means_kernel(
    const float* __restrict__ feat,           // (K, d, N)
    const unsigned short* __restrict__ spos_ws,
    const int* __restrict__ starts_ws,
    float* __restrict__ means_out)            // (S, d)
{
    const int k = blockIdx.x;
    const int chunk = blockIdx.y;
    const int tid = threadIdx.x;

    __shared__ float s_tile[GFEAT][TILEW];      // 34.8 KB
    __shared__ unsigned short s_sp[NP];         // 4 KB
    __shared__ int s_starts[MC + 1];

    {
        const unsigned* spg = (const unsigned*)(spos_ws + (size_t)k * NP);
        for (int i = tid; i < NP / 2; i += 512) ((unsigned*)s_sp)[i] = spg[i];
        if (tid < MC + 1) s_starts[tid] = starts_ws[k * (MC + 1) + tid];
        // zero the 128 pad slots per row once; scatter never touches them
        if (tid < 128) {
#pragma unroll
            for (int r = 0; r < GFEAT; ++r) s_tile[r][17 * tid + 16] = 0.f;
        }
    }
    __syncthreads();

    const int m = tid & 127;   // cluster / staging column group
    const int r = tid >> 7;    // 0..3: feature within group

    unsigned short sp[16];
#pragma unroll
    for (int q = 0; q < 4; ++q) {
        const int p0 = (m + 128 * q) * 4;
#pragma unroll
        for (int e = 0; e < 4; ++e) sp[4 * q + e] = s_sp[p0 + e];
    }

    const int st = s_starts[m];
    const int en = s_starts[m + 1];
    const int ast = st + (st >> 4);     // skewed dense range [ast, aen)
    const int aen = en + (en >> 4);
    const float invd = 1.0f / fmaxf((float)(en - st), 1.0f);

    const float* fb = feat + (size_t)k * DD * NP + (size_t)chunk * CHUNKF * NP;
    float regsum[NGROUP];

#pragma unroll
    for (int g = 0; g < NGROUP; ++g) {
        // issue loads first: latency overlaps prior accumulate + barrier wait
        const float4* src = (const float4*)(fb + (size_t)(g * GFEAT + r) * NP);
        float4 ld[4];
#pragma unroll
        for (int q = 0; q < 4; ++q) ld[q] = src[m + 128 * q];
        if (g > 0) __syncthreads();   // prior accumulate done before overwrite
#pragma unroll
        for (int q = 0; q < 4; ++q) {
            s_tile[r][sp[4 * q + 0]] = ld[q].x;
            s_tile[r][sp[4 * q + 1]] = ld[q].y;
            s_tile[r][sp[4 * q + 2]] = ld[q].z;
            s_tile[r][sp[4 * q + 3]] = ld[q].w;
        }
        __syncthreads();
        // dense skewed segment sum: scalar head to 16B align, b128 body, tail
        float acc = 0.f;
        int a = ast;
        while ((a & 3) && a < aen) { acc += s_tile[r][a]; ++a; }
        while (a + 4 <= aen) {
            const float4 v = *reinterpret_cast<const float4*>(&s_tile[r][a]);
            acc += (v.x + v.y) + (v.z + v.w);
            a += 4;
        }
        while (a < aen) { acc += s_tile[r][a]; ++a; }
        regsum[g] = acc;
    }

    float* mrow = means_out + (size_t)(k * MC + m) * DD + chunk * CHUNKF;
#pragma unroll
    for (int g = 0; g < NGROUP; ++g) mrow[g * GFEAT + r] = regsum[g] * invd;
}

// ---------------------------------------------------------------------------
// Software grid barrier for co-resident blocks (device-scope, XCD-safe).
// ---------------------------------------------------------------------------
__device__ inline void grid_barrier(unsigned* cnt, unsigned nblocks) {
    __syncthreads();   // all waves' stores drained before the release
    if (threadIdx.x == 0) {
        __hip_atomic_fetch_add(cnt, 1u, __ATOMIC_ACQ_REL, __HIP_MEMORY_SCOPE_AGENT);
        while (__hip_atomic_load(cnt, __ATOMIC_ACQUIRE, __HIP_MEMORY_SCOPE_AGENT) < nblocks) {
            __builtin_amdgcn_s_sleep(2);
        }
    }
    __syncthreads();
}

// ---------------------------------------------------------------------------
// Kernel C (fused tail): norm + v-reduce + sim + mean + clean.
// 128 blocks, each owns 64 segments (16 per wave). rw and sim stay in
// registers across phases; two grid barriers.
// ---------------------------------------------------------------------------
__global__ __launch_bounds__(256) void tail_kernel(
    const float* __restrict__ means,   // (S, d)
    const float* __restrict__ cls,     // (S,)
    const float* __restrict__ sizes,   // (S,)
    const float* __restrict__ kmax,    // (K,)
    const float* __restrict__ kval,    // (K,)
    float* __restrict__ vpart,         // (128, d)
    float* __restrict__ simpart,       // (128,)
    unsigned* __restrict__ counters,   // [2]
    float* __restrict__ sim_out,       // (S,)
    float* __restrict__ clean_out)     // (S,)
{
    const int b = blockIdx.x;
    const int tid = threadIdx.x;
    const int wid = tid >> 6;
    const int lane = tid & 63;
    const int seg0 = b * 64 + wid * 16;

    __shared__ float vtmp[4][DD];
    __shared__ float s_v[DD];
    __shared__ float stmp[4];
    __shared__ float s_rmx, s_nvalid, s_mean;

    if (wid == 0) {
        float mv = kmax[lane];
        float nv = kval[lane];
#pragma unroll
        for (int off = 32; off > 0; off >>= 1) {
            mv = fmaxf(mv, __shfl_xor(mv, off, 64));
            nv += __shfl_xor(nv, off, 64);
        }
        if (lane == 0) {
            s_rmx = 1.0f / fmaxf(mv, 1.0f);
            s_nvalid = fmaxf(nv, 1.0f);
        }
    }
    __syncthreads();
    const float rmx = s_rmx;

    // ---- phase 1: norms, rw (regs), v partial ----
    float rw[16];
    float vacc[5] = {0.f, 0.f, 0.f, 0.f, 0.f};
#pragma unroll
    for (int i = 0; i < 16; ++i) {
        const int s = seg0 + i;
        const float* row = means + (size_t)s * DD;
        float val[5];
        float ssum = 0.f;
#pragma unroll
        for (int r = 0; r < 5; ++r) {
            val[r] = row[r * 64 + lane];
            ssum = fmaf(val[r], val[r], ssum);
        }
#pragma unroll
        for (int off = 32; off > 0; off >>= 1) ssum += __shfl_xor(ssum, off, 64);
        const float inv = 1.f / fmaxf(sqrtf(ssum), EPSV);
        rw[i] = cls[s] * inv;
        const float coef = sizes[s] * rmx * rw[i];
#pragma unroll
        for (int r = 0; r < 5; ++r) vacc[r] = fmaf(coef, val[r], vacc[r]);
    }
#pragma unroll
    for (int r = 0; r < 5; ++r) vtmp[wid][r * 64 + lane] = vacc[r];
    __syncthreads();
    for (int j = tid; j < DD; j += 256) {
        vpart[(size_t)b * DD + j] = vtmp[0][j] + vtmp[1][j] + vtmp[2][j] + vtmp[3][j];
    }

    grid_barrier(&counters[0], TAILB);

    // ---- phase 2: reduce v, then sim ----
    for (int j = tid; j < DD; j += 256) {
        float acc = 0.f;
        for (int bb = 0; bb < TAILB; ++bb) acc += vpart[(size_t)bb * DD + j];
        s_v[j] = acc;
    }
    __syncthreads();

    float vreg[5];
#pragma unroll
    for (int r = 0; r < 5; ++r) vreg[r] = s_v[r * 64 + lane];

    float sim[16];
    float lsum = 0.f;
#pragma unroll
    for (int i = 0; i < 16; ++i) {
        const int s = seg0 + i;
        const float* row = means + (size_t)s * DD;
        float dot = 0.f;
#pragma unroll
        for (int r = 0; r < 5; ++r) dot = fmaf(row[r * 64 + lane], vreg[r], dot);
#pragma unroll
        for (int off = 32; off > 0; off >>= 1) dot += __shfl_xor(dot, off, 64);
        sim[i] = rw[i] * dot;
        lsum += sim[i];
        if (lane == 0) sim_out[s] = sim[i];
    }
    if (lane == 0) stmp[wid] = lsum;
    __syncthreads();
    if (tid == 0) simpart[b] = stmp[0] + stmp[1] + stmp[2] + stmp[3];

    grid_barrier(&counters[1], TAILB);

    // ---- phase 3: mean score + clean mask ----
    if (wid == 0) {
        float t = simpart[lane] + simpart[lane + 64];
#pragma unroll
        for (int off = 32; off > 0; off >>= 1) t += __shfl_xor(t, off, 64);
        if (lane == 0) s_mean = t / s_nvalid;
    }
    __syncthreads();
    const float mean = s_mean;
    if (lane == 0) {
#pragma unroll
        for (int i = 0; i < 16; ++i) {
            clean_out[seg0 + i] = (sim[i] > mean && rw[i] > 0.f) ? 1.f : 0.f;
        }
    }
}

extern "C" void kernel_launch(void* const* d_in, const int* in_sizes, int n_in,
                              void* d_out, int out_size, void* d_ws, size_t ws_size,
                              hipStream_t stream) {
    const float* feat  = (const float*)d_in[0];
    const float* label = (const float*)d_in[1];
    const int*   clab  = (const int*)d_in[2];

    float* out       = (float*)d_out;
    float* means_out = out;
    float* sim_out   = out + (size_t)SS * DD;
    float* clean_out = sim_out + SS;

    // workspace layout (floats)
    float* ws = (float*)d_ws;
    unsigned* counters = (unsigned*)&ws[0];          // 2 u32
    float* kmax    = &ws[4];                         // 64
    float* kval    = &ws[68];                        // 64
    float* simpart = &ws[132];                       // 128
    float* vpart   = &ws[260];                       // 128*320
    float* cls     = vpart + TAILB * DD;             // 8192
    float* sizes   = cls + SS;                       // 8192
    int*   starts  = (int*)(sizes + SS);             // 64*129
    unsigned short* spos = (unsigned short*)(starts + KC * (MC + 1)); // 64*2048 u16

    sortstats_kernel<<<KC, 256, 0, stream>>>(label, clab, spos, starts,
                                             cls, sizes, kmax, kval, counters);
    means_kernel<<<dim3(KC, NCHUNKF), 512, 0, stream>>>(feat, spos, starts, means_out);
    tail_kernel<<<TAILB, 256, 0, stream>>>(means_out, cls, sizes, kmax, kval,
                                           vpart, simpart, counters,
                                           sim_out, clean_out);
}